// Round 13
// baseline (2352.408 us; speedup 1.0000x reference)
//
#include <hip/hip_runtime.h>
#include <hip/hip_bf16.h>
#include <stdint.h>

typedef __attribute__((ext_vector_type(8))) _Float16 half8;
typedef __attribute__((ext_vector_type(4))) float f32x4;
typedef __attribute__((ext_vector_type(16))) float f32x16;

#define N_TOK  65536
#define DIM    256
#define NT     76          // 32-cluster tiles: 69 (L0) + 6 (L1) + 1 (L2)
#define TAU    0.12f
#define MAXFL  8192        // per-layer flag cap

// padded layer map: L0 tiles [0,69) base 0 size 2197
//                   L1 tiles [69,75) base 2208 size 169
//                   L2 tile  75 base 2400 size 13

// workspace layout (bytes):
// 0       : int cnt[3] (per-layer flag counters)
// 64      : flag lists, 3 layers x 8192 int  (WS_FLAGS(L))
// 98368   : wnorm, 2432 floats (padded index)
// 131072  : fp16 hi W-frags, 76 tiles * 16KB
#define WS_FLAGS(L) (64 + (L) * 32768)
#define WS_WNORM    98368
#define WS_WHFRAG   131072

// -------- prep: pack W into 32x32x16 MFMA A-frag order (fp16 hi) + fp64 wnorm --
__global__ void prep_kernel(const float* __restrict__ w0, const float* __restrict__ w1,
                            const float* __restrict__ w2, unsigned char* __restrict__ ws) {
  const int t = blockIdx.x;
  const int tid = threadIdx.x;           // 256 threads
  const float* wsrc; int basePad, csize;
  if (t < 69)      { wsrc = w0; basePad = 0;    csize = 2197; }
  else if (t < 75) { wsrc = w1; basePad = 2208; csize = 169;  }
  else             { wsrc = w2; basePad = 2400; csize = 13;   }
  half8* whf = (half8*)(ws + WS_WHFRAG);
#pragma unroll
  for (int r = 0; r < 4; ++r) {
    int q = r * 256 + tid;               // frag slot within tile
    int l = q & 63;
    int s = q >> 6;                      // 0..15
    int cit = l & 31;
    int k = s * 16 + (l >> 5) * 8;
    int cl = t * 32 + cit - basePad;
    float xs[8];
    if (cl < csize) {
      const float4* p = (const float4*)(wsrc + (size_t)cl * DIM + k);
      float4 a = p[0], b = p[1];
      xs[0]=a.x; xs[1]=a.y; xs[2]=a.z; xs[3]=a.w; xs[4]=b.x; xs[5]=b.y; xs[6]=b.z; xs[7]=b.w;
    } else {
#pragma unroll
      for (int j = 0; j < 8; ++j) xs[j] = 0.0f;
    }
    half8 h;
#pragma unroll
    for (int j = 0; j < 8; ++j) h[j] = (_Float16)xs[j];
    whf[(size_t)t * 1024 + q] = h;
  }
  // wnorm: 8 threads per cluster, fp64, shuffle-reduce
  {
    int gid = tid >> 3, j = tid & 7;     // gid 0..31
    int cl = t * 32 + gid - basePad;
    double acc = 0.0;
    if (cl >= 0 && cl < csize) {
      const float* row = wsrc + (size_t)cl * DIM + j * 32;
#pragma unroll
      for (int k = 0; k < 32; ++k) { double x = row[k]; acc += x * x; }
    }
    acc += __shfl_xor(acc, 1, 64);
    acc += __shfl_xor(acc, 2, 64);
    acc += __shfl_xor(acc, 4, 64);
    if (j == 0) {
      float* wn = (float*)(ws + WS_WNORM);
      wn[t * 32 + gid] = (cl >= 0 && cl < csize) ? (float)acc : __builtin_inff();
    }
  }
  if (t == 0 && tid < 3) ((int*)ws)[tid] = 0;
}

// -------- main: 64 tok/wave (2 MFMA B-groups), barrier-free A/B streaming -----
__global__ __launch_bounds__(128, 1) void argmin_kernel(
    const float* __restrict__ E, const float* __restrict__ w0, const float* __restrict__ w1,
    const float* __restrict__ w2, float* __restrict__ out, unsigned char* __restrict__ ws) {
  const int tid   = threadIdx.x;
  const int lane  = tid & 63;
  const int wave  = tid >> 6;    // 0..1
  const int col   = lane & 31;   // token within 32-tile
  const int khalf = lane >> 5;   // 0/1 (k sub-block / C-row offset)
  const int tokA  = blockIdx.x * 128 + wave * 64;   // group A token base
  const int tokB  = tokA + 32;                      // group B token base

  // E fragments (B-operand): lane holds E[tok=base+col][k = s*16 + khalf*8 + j]
  half8 ehA[16], ehB[16];
#pragma unroll
  for (int s = 0; s < 16; ++s) {
    {
      const float4* p = (const float4*)(E + (size_t)(tokA + col) * DIM + s * 16 + khalf * 8);
      float4 a = p[0], b = p[1];
      float xs[8] = {a.x, a.y, a.z, a.w, b.x, b.y, b.z, b.w};
      half8 h;
#pragma unroll
      for (int j = 0; j < 8; ++j) h[j] = (_Float16)xs[j];
      ehA[s] = h;
    }
    {
      const float4* p = (const float4*)(E + (size_t)(tokB + col) * DIM + s * 16 + khalf * 8);
      float4 a = p[0], b = p[1];
      float xs[8] = {a.x, a.y, a.z, a.w, b.x, b.y, b.z, b.w};
      half8 h;
#pragma unroll
      for (int j = 0; j < 8; ++j) h[j] = (_Float16)xs[j];
      ehB[s] = h;
    }
  }

  const half8* whf = (const half8*)(ws + WS_WHFRAG);
  const float* wn  = (const float*)(ws + WS_WNORM);

  float v1A = __builtin_inff(), v2A = __builtin_inff();
  float v1B = __builtin_inff(), v2B = __builtin_inff();
  int   i1A = 0x7fffffff, i1B = 0x7fffffff;

#define LOADW(DST, T) { const half8* p_ = whf + (size_t)(T) * 1024; _Pragma("unroll") \
    for (int s = 0; s < 16; ++s) DST[s] = p_[s * 64 + lane]; }

  // two independent MFMA chains (groups A/B share W frags) + fused epilogue
#define TILE(REGS, T)                                                        \
  {                                                                          \
    f32x16 aA = (f32x16){0.f,0.f,0.f,0.f,0.f,0.f,0.f,0.f,                    \
                         0.f,0.f,0.f,0.f,0.f,0.f,0.f,0.f};                   \
    f32x16 aB = aA;                                                          \
    _Pragma("unroll")                                                        \
    for (int s = 0; s < 16; ++s) {                                           \
      aA = __builtin_amdgcn_mfma_f32_32x32x16_f16(REGS[s], ehA[s], aA, 0, 0, 0); \
      aB = __builtin_amdgcn_mfma_f32_32x32x16_f16(REGS[s], ehB[s], aB, 0, 0, 0); \
    }                                                                        \
    _Pragma("unroll")                                                        \
    for (int q = 0; q < 4; ++q) {                                            \
      float4 w4 = *(const float4*)(wn + (T) * 32 + q * 8 + khalf * 4);       \
      float wv[4] = {w4.x, w4.y, w4.z, w4.w};                                \
      _Pragma("unroll")                                                      \
      for (int rr = 0; rr < 4; ++rr) {                                       \
        int c = (T) * 32 + rr + 8 * q + 4 * khalf;                           \
        { float d = __builtin_fmaf(-2.0f, aA[q * 4 + rr], wv[rr]);           \
          bool lt = d < v1A; float hi = fmaxf(d, v1A);                       \
          v1A = fminf(d, v1A); v2A = fminf(v2A, hi); i1A = lt ? c : i1A; }   \
        { float d = __builtin_fmaf(-2.0f, aB[q * 4 + rr], wv[rr]);           \
          bool lt = d < v1B; float hi = fmaxf(d, v1B);                       \
          v1B = fminf(d, v1B); v2B = fminf(v2B, hi); i1B = lt ? c : i1B; }   \
      }                                                                      \
    }                                                                        \
  }

  // per-group finalize: khalf merge, near-tie flag (per-layer list), row write
#define FIN1(LVAL, BASEPAD, WLP, V1, V2, I1, TB)                             \
  {                                                                          \
    float o1 = __shfl_xor(V1, 32, 64);                                       \
    int   oi = __shfl_xor(I1, 32, 64);                                       \
    float o2 = __shfl_xor(V2, 32, 64);                                       \
    float a1 = fminf(V1, o1);                                                \
    float a2 = fminf(fmaxf(V1, o1), fminf(V2, o2));                          \
    int   b1 = (o1 < V1) ? oi : I1;                                          \
    int li = b1 - (BASEPAD);                                                 \
    if (khalf == 0 && (a2 - a1 < TAU)) {                                     \
      int pos = atomicAdd((int*)ws + (LVAL), 1);                             \
      if (pos < MAXFL) ((int*)(ws + WS_FLAGS(LVAL)))[pos] = (TB) + col;      \
    }                                                                        \
    _Pragma("unroll 1")                                                      \
    for (int r = 0; r < 32; ++r) {                                           \
      int ir = __shfl(li, r, 64);                                            \
      const f32x4* src = (const f32x4*)((WLP) + (size_t)ir * DIM);           \
      f32x4* dst = (f32x4*)(out + ((size_t)((LVAL) * N_TOK + (TB) + r)) * DIM); \
      __builtin_nontemporal_store(src[lane], &dst[lane]);                    \
    }                                                                        \
    V1 = __builtin_inff(); V2 = __builtin_inff(); I1 = 0x7fffffff;           \
  }

  half8 wA[16], wB[16];
  LOADW(wA, 0);

#pragma unroll 1
  for (int it = 0; it < NT / 2; ++it) {
    const int t0 = 2 * it, t1 = t0 + 1;
    LOADW(wB, t1);
    TILE(wA, t0);
    if (t0 == 68) { FIN1(0, 0, w0, v1A, v2A, i1A, tokA); FIN1(0, 0, w0, v1B, v2B, i1B, tokB); }
    if (t0 == 74) { FIN1(1, 2208, w1, v1A, v2A, i1A, tokA); FIN1(1, 2208, w1, v1B, v2B, i1B, tokB); }
    if (it + 1 < NT / 2) LOADW(wA, t0 + 2);
    TILE(wB, t1);
    if (t1 == 75) { FIN1(2, 2400, w2, v1A, v2A, i1A, tokA); FIN1(2, 2400, w2, v1B, v2B, i1B, tokB); }
  }
#undef LOADW
#undef TILE
#undef FIN1
}

// ------- refine: BLOCK per 4-flag quad; 4 waves split the cluster range ------
// E rows (4 x 1KB) staged in LDS, uniform-address b128 broadcasts (free).
// Lane l scans rows cb+l / cb+64+l of its wave's quarter-range; k-loop is
// hand-pipelined 2-deep (next-step W loads issued before this step's FMAs).
// All accumulators are NAMED scalars/vectors (no arrays -> no scratch).
// Cross-wave merge via LDS; wave w writes flag w's winner row coalesced.
__device__ __forceinline__ f32x4 vfma4(f32x4 a, f32x4 b, f32x4 c) {
  f32x4 r;
  r.x = __builtin_fmaf(a.x, b.x, c.x);
  r.y = __builtin_fmaf(a.y, b.y, c.y);
  r.z = __builtin_fmaf(a.z, b.z, c.z);
  r.w = __builtin_fmaf(a.w, b.w, c.w);
  return r;
}

__global__ __launch_bounds__(256) void refine_kernel(
    const float* __restrict__ E, const float* __restrict__ w0,
    const float* __restrict__ w1, const float* __restrict__ w2,
    float* __restrict__ out, unsigned char* __restrict__ ws) {
  const int tid  = threadIdx.x;
  const int lane = tid & 63;
  const int wave = tid >> 6;
  const int* cnt = (const int*)ws;
  int c0 = cnt[0] < MAXFL ? cnt[0] : MAXFL;
  int c1 = cnt[1] < MAXFL ? cnt[1] : MAXFL;
  int c2 = cnt[2] < MAXFL ? cnt[2] : MAXFL;
  int q0 = (c0 + 3) >> 2, q1 = (c1 + 3) >> 2, q2 = (c2 + 3) >> 2;
  int qtot = q0 + q1 + q2;
  const float* wn = (const float*)(ws + WS_WNORM);

  __shared__ __align__(16) float esh[4][256];  // 4 E rows, 4KB
  __shared__ float pd[4][4];                   // [wave][flag]
  __shared__ int   pi[4][4];
  __shared__ int   tks[4];

  const float INF = __builtin_inff();

  for (int qi = blockIdx.x; qi < qtot; qi += gridDim.x) {
    int L, qb, cl, csize, basePad; const float* WL;
    if (qi < q0)           { L = 0; qb = qi;           cl = c0; WL = w0; csize = 2197; basePad = 0; }
    else if (qi < q0 + q1) { L = 1; qb = qi - q0;      cl = c1; WL = w1; csize = 169;  basePad = 2208; }
    else                   { L = 2; qb = qi - q0 - q1; cl = c2; WL = w2; csize = 13;   basePad = 2400; }
    const int* fl = (const int*)(ws + WS_FLAGS(L));
    int f0 = qb * 4;
    int mv = cl - f0; mv = mv < 4 ? mv : 4;    // 1..4 valid flags
    __syncthreads();                           // protect LDS reuse across quads
    if (tid < 4) tks[tid] = fl[f0 + (tid < mv ? tid : 0)];
    __syncthreads();
    // stage 4 E rows (coalesced: thread tid loads row tid>>6, slot tid&63)
    *(f32x4*)&esh[tid >> 6][(tid & 63) * 4] =
        ((const f32x4*)(E + (size_t)tks[tid >> 6] * DIM))[tid & 63];
    __syncthreads();

    // this wave's cluster quarter-range
    int per = (csize + 3) >> 2;
    int r0 = wave * per;
    int r1 = r0 + per; r1 = r1 < csize ? r1 : csize;

    float bd0 = INF, bd1 = INF, bd2 = INF, bd3 = INF;
    int   bi0 = 0x7fffffff, bi1 = 0x7fffffff, bi2 = 0x7fffffff, bi3 = 0x7fffffff;

#pragma unroll 1
    for (int cb = r0; cb < r1; cb += 128) {
      const int ca = cb + lane;
      const int cbh = ca + 64;
      const bool oka = ca < r1;
      const bool okb = cbh < r1;
      const f32x4* ra = (const f32x4*)(WL + (size_t)(oka ? ca : 0) * DIM);
      const f32x4* rb = (const f32x4*)(WL + (size_t)(okb ? cbh : 0) * DIM);
      f32x4 z = (f32x4){0.f, 0.f, 0.f, 0.f};
      f32x4 da0 = z, da1 = z, da2 = z, da3 = z;
      f32x4 db0 = z, db1 = z, db2 = z, db3 = z;
      // 2-deep pipelined k-loop: issue k+1 loads before k's FMA pack
      f32x4 wa = ra[0], wb = rb[0];
#pragma unroll
      for (int k = 0; k < 64; ++k) {
        f32x4 wan = z, wbn = z;
        if (k < 63) { wan = ra[k + 1]; wbn = rb[k + 1]; }
        f32x4 e0 = *(const f32x4*)&esh[0][k * 4];
        f32x4 e1 = *(const f32x4*)&esh[1][k * 4];
        f32x4 e2 = *(const f32x4*)&esh[2][k * 4];
        f32x4 e3 = *(const f32x4*)&esh[3][k * 4];
        da0 = vfma4(wa, e0, da0); da1 = vfma4(wa, e1, da1);
        da2 = vfma4(wa, e2, da2); da3 = vfma4(wa, e3, da3);
        db0 = vfma4(wb, e0, db0); db1 = vfma4(wb, e1, db1);
        db2 = vfma4(wb, e2, db2); db3 = vfma4(wb, e3, db3);
        wa = wan; wb = wbn;
      }
      float wna = oka ? wn[basePad + ca] : INF;
      float wnb = okb ? wn[basePad + cbh] : INF;
#define UPD(BD, BI, ACC, WNV, C, OK)                                         \
      { float s_ = ((ACC).x + (ACC).y) + ((ACC).z + (ACC).w);                \
        float d_ = (OK) ? __builtin_fmaf(-2.0f, s_, (WNV)) : INF;            \
        bool lt_ = (d_ < (BD)) || (d_ == (BD) && (C) < (BI));                \
        BD = lt_ ? d_ : (BD); BI = lt_ ? (C) : (BI); }
      UPD(bd0, bi0, da0, wna, ca, oka); UPD(bd0, bi0, db0, wnb, cbh, okb);
      UPD(bd1, bi1, da1, wna, ca, oka); UPD(bd1, bi1, db1, wnb, cbh, okb);
      UPD(bd2, bi2, da2, wna, ca, oka); UPD(bd2, bi2, db2, wnb, cbh, okb);
      UPD(bd3, bi3, da3, wna, ca, oka); UPD(bd3, bi3, db3, wnb, cbh, okb);
#undef UPD
    }
    // in-wave xor-reduce per flag
#define RED(BD, BI)                                                          \
    { _Pragma("unroll")                                                      \
      for (int off = 1; off < 64; off <<= 1) {                               \
        float od = __shfl_xor(BD, off, 64);                                  \
        int   oi = __shfl_xor(BI, off, 64);                                  \
        bool tk = (od < (BD)) || (od == (BD) && oi < (BI));                  \
        BD = tk ? od : (BD); BI = tk ? oi : (BI);                            \
      } }
    RED(bd0, bi0); RED(bd1, bi1); RED(bd2, bi2); RED(bd3, bi3);
#undef RED
    if (lane == 0) {
      pd[wave][0] = bd0; pi[wave][0] = bi0;
      pd[wave][1] = bd1; pi[wave][1] = bi1;
      pd[wave][2] = bd2; pi[wave][2] = bi2;
      pd[wave][3] = bd3; pi[wave][3] = bi3;
    }
    __syncthreads();
    // wave w finalizes flag w: merge 4 wave-partials, write winner row
    {
      float b = pd[0][wave]; int x = pi[0][wave];
#pragma unroll
      for (int wv = 1; wv < 4; ++wv) {
        float ob = pd[wv][wave]; int ox = pi[wv][wave];
        bool tk = (ob < b) || (ob == b && ox < x);
        b = tk ? ob : b; x = tk ? ox : x;
      }
      const f32x4* s = (const f32x4*)(WL + (size_t)x * DIM);
      f32x4* d = (f32x4*)(out + ((size_t)(L * N_TOK + tks[wave])) * DIM);
      d[lane] = s[lane];
    }
  }
}

extern "C" void kernel_launch(void* const* d_in, const int* in_sizes, int n_in,
                              void* d_out, int out_size, void* d_ws, size_t ws_size,
                              hipStream_t stream) {
  const float* E  = (const float*)d_in[0];
  const float* w0 = (const float*)d_in[1];
  const float* w1 = (const float*)d_in[2];
  const float* w2 = (const float*)d_in[3];
  float* out = (float*)d_out;
  unsigned char* ws = (unsigned char*)d_ws;

  hipLaunchKernelGGL(prep_kernel,   dim3(NT),  dim3(256), 0, stream, w0, w1, w2, ws);
  hipLaunchKernelGGL(argmin_kernel, dim3(512), dim3(128), 0, stream, E, w0, w1, w2, out, ws);
  hipLaunchKernelGGL(refine_kernel, dim3(512), dim3(256), 0, stream, E, w0, w1, w2, out, ws);
}